// Round 2
// baseline (1794.478 us; speedup 1.0000x reference)
//
#include <hip/hip_runtime.h>
#include <cstdint>
#include <cstddef>

#define NN 131072
#define EE 524288
#define GG 4096
#define NPASS 4

typedef __attribute__((ext_vector_type(4))) float f32x4;
typedef __attribute__((ext_vector_type(8))) short bfrag;

__device__ __forceinline__ unsigned short f2bf(float f) {
  union { float f; unsigned u; } v; v.f = f;
  unsigned r = v.u + 0x7fffu + ((v.u >> 16) & 1u);
  return (unsigned short)(r >> 16);
}
__device__ __forceinline__ float bf2f(unsigned short h) {
  union { unsigned u; float f; } v; v.u = ((unsigned)h) << 16;
  return v.f;
}
__device__ __forceinline__ unsigned pack2(float x, float y) {
  return (unsigned)f2bf(x) | ((unsigned)f2bf(y) << 16);
}

// ---------------- weight prep ----------------
__global__ void prep_wb(const float* __restrict__ Wmsg, unsigned short* __restrict__ Wb) {
  int idx = blockIdx.x * 256 + threadIdx.x;  // 256*512
  if (idx >= 256 * 512) return;
  int m = idx >> 9, k = idx & 511;
  int t = k >> 7, d = k & 127;
  Wb[idx] = f2bf(Wmsg[((size_t)t * 256 + m) * 128 + d]);
}

__global__ void prep_wgru(const float* __restrict__ Wih, const float* __restrict__ Whh,
                          unsigned short* __restrict__ Wgru) {
  int idx = blockIdx.x * 256 + threadIdx.x;  // 512*384
  if (idx >= 512 * 384) return;
  int j = idx / 384, kk = idx % 384;
  float v;
  if (kk < 256) v = (j < 384) ? Wih[j * 256 + kk] : 0.f;
  else          v = (j < 256) ? Whh[j * 128 + (kk - 256)]
                   : ((j >= 384) ? Whh[(j - 128) * 128 + (kk - 256)] : 0.f);
  Wgru[idx] = f2bf(v);
}

__global__ void prep_bias(const float* __restrict__ bih, const float* __restrict__ bhh,
                          float* __restrict__ biasg) {
  int j = blockIdx.x * 256 + threadIdx.x;
  if (j >= 512) return;
  biasg[j] = (j < 256) ? (bih[j] + bhh[j]) : (j < 384 ? bih[j] : bhh[j - 128]);
}

__global__ void prep_wn2g(const float* __restrict__ Wn, unsigned short* __restrict__ Wo) {
  int idx = blockIdx.x * 256 + threadIdx.x;  // 512*128
  if (idx >= 512 * 128) return;
  Wo[idx] = f2bf(Wn[idx]);
}

// ---------------- init ----------------
__global__ void init_h(const int* __restrict__ nt, const float* __restrict__ emb,
                       unsigned short* __restrict__ A2) {
  size_t idx = (size_t)blockIdx.x * 256 + threadIdx.x;  // N*128
  int n = (int)(idx >> 7), d = (int)(idx & 127);
  A2[(size_t)n * 384 + 256 + d] = f2bf(emb[(size_t)nt[n] * 128 + d]);
}

// ---------------- CSR build (once per call) ----------------
__global__ void deg_k(const int* __restrict__ edst, int* __restrict__ deg) {
  int e = blockIdx.x * 256 + threadIdx.x;
  if (e >= EE) return;
  atomicAdd(&deg[edst[e]], 1);
}

__global__ void cnt_k(const int* __restrict__ edst, const int* __restrict__ etype,
                      float* __restrict__ cnt) {
  int e = blockIdx.x * 256 + threadIdx.x;
  if (e >= EE) return;
  unsafeAtomicAdd(&cnt[(size_t)edst[e] * 4 + etype[e]], 1.0f);
}

__global__ __launch_bounds__(1024) void scan_k(const int* __restrict__ deg,
                                               int* __restrict__ rowptr,
                                               int* __restrict__ cursor) {
  __shared__ int part[1024];
  int t = threadIdx.x;
  int base = t * 128;
  int s = 0;
  for (int i = 0; i < 128; i++) s += deg[base + i];
  part[t] = s;
  __syncthreads();
  for (int off = 1; off < 1024; off <<= 1) {
    int v = (t >= off) ? part[t - off] : 0;
    __syncthreads();
    part[t] += v;
    __syncthreads();
  }
  int run = part[t] - s;  // exclusive prefix
  for (int i = 0; i < 128; i++) {
    rowptr[base + i] = run;
    cursor[base + i] = run;
    run += deg[base + i];
  }
  if (t == 1023) rowptr[NN] = run;
}

__global__ void fill_k(const int* __restrict__ esrc, const int* __restrict__ edst,
                       const int* __restrict__ etype, int* __restrict__ cursor,
                       unsigned* __restrict__ epack) {
  int e = blockIdx.x * 256 + threadIdx.x;
  if (e >= EE) return;
  int pos = atomicAdd(&cursor[edst[e]], 1);
  epack[pos] = ((unsigned)etype[e] << 17) | (unsigned)esrc[e];
}

// ---------------- per-pass aggregation: s[n, t*128+d] = sum h[src] (bf16 out) ----------------
__global__ __launch_bounds__(256) void agg_k(const int* __restrict__ rowptr,
                                             const unsigned* __restrict__ epack,
                                             const unsigned short* __restrict__ A2,
                                             unsigned short* __restrict__ s) {
  int n = blockIdx.x * 4 + (threadIdx.x >> 6);
  int lane = threadIdx.x & 63;
  int beg = rowptr[n], end = rowptr[n + 1];
  float a0 = 0.f, a1 = 0.f, b0 = 0.f, b1 = 0.f;
  float c0 = 0.f, c1 = 0.f, d0 = 0.f, d1 = 0.f;
  for (int e = beg; e < end; e++) {
    unsigned p = epack[e];  // wave-uniform
    int src = (int)(p & 0x1FFFFu);
    int t = (int)(p >> 17);
    unsigned hv = *(const unsigned*)&A2[(size_t)src * 384 + 256 + lane * 2];
    float v0 = bf2f((unsigned short)(hv & 0xffffu));
    float v1 = bf2f((unsigned short)(hv >> 16));
    if (t == 0)      { a0 += v0; a1 += v1; }
    else if (t == 1) { b0 += v0; b1 += v1; }
    else if (t == 2) { c0 += v0; c1 += v1; }
    else             { d0 += v0; d1 += v1; }
  }
  unsigned short* srow = s + (size_t)n * 512;
  *(unsigned*)&srow[0 * 128 + lane * 2] = pack2(a0, a1);
  *(unsigned*)&srow[1 * 128 + lane * 2] = pack2(b0, b1);
  *(unsigned*)&srow[2 * 128 + lane * 2] = pack2(c0, c1);
  *(unsigned*)&srow[3 * 128 + lane * 2] = pack2(d0, d1);
}

// ---------------- 128x128-tile MFMA GEMM: out = A(NxK,bf16) @ W(JxK)^T ----------------
// MODE 0: agg epilogue (+cnt*b_msg, relu) -> bf16 m into A2 (ld 384)
// MODE 2: (+b_n2g)*gate[i] -> bf16 ghg (ld 512)
template <int MODE>
__global__ __launch_bounds__(256) void gemm_k(const unsigned short* __restrict__ A, int lda,
                                              const unsigned short* __restrict__ W, int K,
                                              void* __restrict__ Out,
                                              const float* __restrict__ aux1,
                                              const float* __restrict__ aux2) {
  __shared__ __align__(16) unsigned short As[128 * 32];
  __shared__ __align__(16) unsigned short Ws[128 * 32];
  int i0 = blockIdx.x * 128;
  int j0 = blockIdx.y * 128;
  int tid = threadIdx.x;
  int lane = tid & 63, w = tid >> 6;
  int wi = w >> 1, wj = w & 1;
  int q = lane >> 4, r = lane & 15;

  f32x4 acc[4][4];
#pragma unroll
  for (int a = 0; a < 4; a++)
#pragma unroll
    for (int b = 0; b < 4; b++) acc[a][b] = f32x4{0.f, 0.f, 0.f, 0.f};

  int srow = tid >> 2;       // 0..63
  int scol = (tid & 3) * 8;  // 0,8,16,24

  for (int k0 = 0; k0 < K; k0 += 32) {
#pragma unroll
    for (int c = 0; c < 2; c++) {
      int row = srow + c * 64;
      *(uint4*)&As[row * 32 + scol] =
          *(const uint4*)&A[(size_t)(i0 + row) * lda + (k0 + scol)];
      *(uint4*)&Ws[row * 32 + scol] =
          *(const uint4*)&W[(size_t)(j0 + row) * K + (k0 + scol)];
    }
    __syncthreads();
    bfrag af[4], bfr[4];
#pragma unroll
    for (int rt = 0; rt < 4; rt++)
      af[rt] = *(const bfrag*)&As[(wi * 64 + rt * 16 + r) * 32 + q * 8];
#pragma unroll
    for (int ct = 0; ct < 4; ct++)
      bfr[ct] = *(const bfrag*)&Ws[(wj * 64 + ct * 16 + r) * 32 + q * 8];
#pragma unroll
    for (int rt = 0; rt < 4; rt++)
#pragma unroll
      for (int ct = 0; ct < 4; ct++)
        acc[rt][ct] =
            __builtin_amdgcn_mfma_f32_16x16x32_bf16(af[rt], bfr[ct], acc[rt][ct], 0, 0, 0);
    __syncthreads();
  }

#pragma unroll
  for (int rt = 0; rt < 4; rt++) {
#pragma unroll
    for (int ct = 0; ct < 4; ct++) {
#pragma unroll
      for (int reg = 0; reg < 4; reg++) {
        int i = i0 + wi * 64 + rt * 16 + q * 4 + reg;
        int j = j0 + wj * 64 + ct * 16 + r;
        float v = acc[rt][ct][reg];
        if (MODE == 0) {
          const float* cnt = aux1 + (size_t)i * 4;
          v += cnt[0] * aux2[j] + cnt[1] * aux2[256 + j] + cnt[2] * aux2[512 + j] +
               cnt[3] * aux2[768 + j];
          v = v > 0.f ? v : 0.f;
          ((unsigned short*)Out)[(size_t)i * 384 + j] = f2bf(v);
        } else {
          v = (v + aux1[j]) * aux2[i];
          ((unsigned short*)Out)[(size_t)i * 512 + j] = f2bf(v);
        }
      }
    }
  }
}

// ---------------- fused GRU GEMM: 32 nodes/block, all 512 cols, K=384 ----------------
__global__ __launch_bounds__(256) void gemm_gru(unsigned short* __restrict__ A2,
                                                const unsigned short* __restrict__ Wgru,
                                                const float* __restrict__ biasg) {
  // lds layout phase 1: As[0..1024) (32x32), Ws[1024..17408) (512x32)
  // lds layout phase 2: Ub[0..16384) (32x512 bf16)
  __shared__ __align__(16) unsigned short lds[17408];
  int i0 = blockIdx.x * 32;
  int tid = threadIdx.x, lane = tid & 63, w = tid >> 6;
  int q = lane >> 4, r = lane & 15;

  f32x4 acc[2][8];
#pragma unroll
  for (int a = 0; a < 2; a++)
#pragma unroll
    for (int b = 0; b < 8; b++) acc[a][b] = f32x4{0.f, 0.f, 0.f, 0.f};

  for (int k0 = 0; k0 < 384; k0 += 32) {
#pragma unroll
    for (int it = 0; it < 8; it++) {
      int row = it * 64 + (tid >> 2);
      int scol = (tid & 3) * 8;
      *(uint4*)&lds[1024 + row * 32 + scol] =
          *(const uint4*)&Wgru[(size_t)row * 384 + k0 + scol];
    }
    if (tid < 128) {
      int row = tid >> 2, scol = (tid & 3) * 8;
      *(uint4*)&lds[row * 32 + scol] =
          *(const uint4*)&A2[(size_t)(i0 + row) * 384 + k0 + scol];
    }
    __syncthreads();
    bfrag af[2], bfr[8];
#pragma unroll
    for (int rt = 0; rt < 2; rt++)
      af[rt] = *(const bfrag*)&lds[(rt * 16 + r) * 32 + q * 8];
#pragma unroll
    for (int ct = 0; ct < 8; ct++)
      bfr[ct] = *(const bfrag*)&lds[1024 + (w * 128 + ct * 16 + r) * 32 + q * 8];
#pragma unroll
    for (int rt = 0; rt < 2; rt++)
#pragma unroll
      for (int ct = 0; ct < 8; ct++)
        acc[rt][ct] =
            __builtin_amdgcn_mfma_f32_16x16x32_bf16(af[rt], bfr[ct], acc[rt][ct], 0, 0, 0);
    __syncthreads();
  }

  // exchange pre-activations via LDS (bf16)
#pragma unroll
  for (int rt = 0; rt < 2; rt++)
#pragma unroll
    for (int ct = 0; ct < 8; ct++)
#pragma unroll
      for (int reg = 0; reg < 4; reg++) {
        int il = rt * 16 + q * 4 + reg;
        int j = w * 128 + ct * 16 + r;
        lds[il * 512 + j] = f2bf(acc[rt][ct][reg] + biasg[j]);
      }
  __syncthreads();

  // GRU elementwise: 32 nodes x 128 dims
  for (int idx = tid; idx < 32 * 128; idx += 256) {
    int nl = idx >> 7, d = idx & 127;
    float u0 = bf2f(lds[nl * 512 + d]);
    float u1 = bf2f(lds[nl * 512 + 128 + d]);
    float u2 = bf2f(lds[nl * 512 + 256 + d]);
    float u3 = bf2f(lds[nl * 512 + 384 + d]);
    size_t hoff = (size_t)(i0 + nl) * 384 + 256 + d;
    float hold = bf2f(A2[hoff]);
    float rg = 1.f / (1.f + __expf(-u0));
    float zg = 1.f / (1.f + __expf(-u1));
    float ng = tanhf(u2 + rg * u3);
    A2[hoff] = f2bf((1.f - zg) * ng + zg * hold);
  }
}

// ---------------- readout ----------------
__global__ __launch_bounds__(256) void gate_k(const unsigned short* __restrict__ A2,
                                              const float* __restrict__ Wg,
                                              const float* __restrict__ bg,
                                              float* __restrict__ gate) {
  __shared__ float wg[128];
  if (threadIdx.x < 128) wg[threadIdx.x] = Wg[threadIdx.x];
  __syncthreads();
  int g = threadIdx.x >> 4, sub = threadIdx.x & 15;
  int n = blockIdx.x * 16 + g;
  const unsigned short* hr = A2 + (size_t)n * 384 + 256;
  float p = 0.f;
  for (int k = sub; k < 128; k += 16) p += bf2f(hr[k]) * wg[k];
  p += __shfl_xor(p, 1);
  p += __shfl_xor(p, 2);
  p += __shfl_xor(p, 4);
  p += __shfl_xor(p, 8);
  if (sub == 0) gate[n] = 1.f / (1.f + __expf(-(p + bg[0])));
}

__global__ __launch_bounds__(256) void reduce_k(const unsigned short* __restrict__ ghg,
                                                const int* __restrict__ ptr,
                                                float* __restrict__ hgraph) {
  int g = blockIdx.x;
  int start = ptr[g], end = ptr[g + 1];
  int c = threadIdx.x;
  float a0 = 0.f, a1 = 0.f;
  for (int n = start; n < end; n++) {
    const unsigned short* row = ghg + (size_t)n * 512;
    a0 += bf2f(row[c]);
    a1 += bf2f(row[c + 256]);
  }
  hgraph[(size_t)g * 512 + c] = a0;
  hgraph[(size_t)g * 512 + c + 256] = a1;
}

__global__ __launch_bounds__(256) void final_k(const float* __restrict__ hgraph,
                                               const float* __restrict__ Wloc,
                                               const float* __restrict__ bloc,
                                               const float* __restrict__ Wlv,
                                               const float* __restrict__ blv,
                                               float* __restrict__ out) {
  __shared__ float hs[16 * 512];
  int bid = blockIdx.x;
  const float* base = hgraph + (size_t)bid * 16 * 512;
  for (int x = threadIdx.x; x < 16 * 512 / 4; x += 256)
    ((float4*)hs)[x] = ((const float4*)base)[x];
  __syncthreads();
  int j = threadIdx.x;
  const float* wrow = (j < 128) ? (Wloc + (size_t)j * 512) : (Wlv + (size_t)(j - 128) * 512);
  float bias = (j < 128) ? bloc[j] : blv[j - 128];
  float acc[16];
#pragma unroll
  for (int rr = 0; rr < 16; rr++) acc[rr] = bias;
  for (int k = 0; k < 512; k++) {
    float wv = wrow[k];
#pragma unroll
    for (int rr = 0; rr < 16; rr++) acc[rr] += hs[rr * 512 + k] * wv;
  }
#pragma unroll
  for (int rr = 0; rr < 16; rr++) {
    int g = bid * 16 + rr;
    size_t o = (j < 128) ? ((size_t)g * 128 + j)
                         : ((size_t)GG * 128 + (size_t)g * 128 + (j - 128));
    out[o] = acc[rr];
  }
}

extern "C" void kernel_launch(void* const* d_in, const int* in_sizes, int n_in,
                              void* d_out, int out_size, void* d_ws, size_t ws_size,
                              hipStream_t stream) {
  const int* node_types = (const int*)d_in[0];
  const int* esrc = (const int*)d_in[1];
  const int* edst = (const int*)d_in[2];
  const int* etype = (const int*)d_in[3];
  const int* ptr = (const int*)d_in[4];
  const float* emb = (const float*)d_in[5];
  const float* Wmsg = (const float*)d_in[6];
  const float* bmsg = (const float*)d_in[7];
  const float* Wih = (const float*)d_in[8];
  const float* Whh = (const float*)d_in[9];
  const float* bih = (const float*)d_in[10];
  const float* bhh = (const float*)d_in[11];
  const float* Wg = (const float*)d_in[12];
  const float* bg = (const float*)d_in[13];
  const float* Wn2g = (const float*)d_in[14];
  const float* bn2g = (const float*)d_in[15];
  const float* Wloc = (const float*)d_in[16];
  const float* bloc = (const float*)d_in[17];
  const float* Wlv = (const float*)d_in[18];
  const float* blv = (const float*)d_in[19];
  float* out = (float*)d_out;

  char* ws = (char*)d_ws;
  size_t off = 0;
  unsigned short* s = (unsigned short*)(ws);  // N x 512 bf16 (128 MB); ghg aliases
  unsigned short* ghg = s;
  off += (size_t)NN * 512 * 2;
  unsigned short* A2 = (unsigned short*)(ws + off);  // N x 384 bf16: [m(256) | h(128)]
  off += (size_t)NN * 384 * 2;
  float* cnt = (float*)(ws + off);
  off += (size_t)NN * 4 * 4;
  int* deg = (int*)(ws + off);
  off += (size_t)NN * 4;
  int* rowptr = (int*)(ws + off);
  off += (size_t)(NN + 64) * 4;
  int* cursor = (int*)(ws + off);
  off += (size_t)NN * 4;
  unsigned* epack = (unsigned*)(ws + off);
  off += (size_t)EE * 4;
  float* hgraph = (float*)(ws + off);
  off += (size_t)GG * 512 * 4;
  float* gate = (float*)(ws + off);
  off += (size_t)NN * 4;
  unsigned short* Wb = (unsigned short*)(ws + off);
  off += 256 * 512 * 2;
  unsigned short* Wgru = (unsigned short*)(ws + off);
  off += 512 * 384 * 2;
  float* biasg = (float*)(ws + off);
  off += 512 * 4;
  unsigned short* Wn2gb = (unsigned short*)(ws + off);
  off += 512 * 128 * 2;

  hipMemsetAsync(deg, 0, (size_t)NN * 4, stream);
  hipMemsetAsync(cnt, 0, (size_t)NN * 16, stream);
  prep_wb<<<512, 256, 0, stream>>>(Wmsg, Wb);
  prep_wgru<<<768, 256, 0, stream>>>(Wih, Whh, Wgru);
  prep_bias<<<2, 256, 0, stream>>>(bih, bhh, biasg);
  prep_wn2g<<<256, 256, 0, stream>>>(Wn2g, Wn2gb);
  init_h<<<NN * 128 / 256, 256, 0, stream>>>(node_types, emb, A2);
  deg_k<<<EE / 256, 256, 0, stream>>>(edst, deg);
  cnt_k<<<EE / 256, 256, 0, stream>>>(edst, etype, cnt);
  scan_k<<<1, 1024, 0, stream>>>(deg, rowptr, cursor);
  fill_k<<<EE / 256, 256, 0, stream>>>(esrc, edst, etype, cursor, epack);

  for (int p = 0; p < NPASS; p++) {
    agg_k<<<NN / 4, 256, 0, stream>>>(rowptr, epack, A2, s);
    gemm_k<0><<<dim3(NN / 128, 2), 256, 0, stream>>>(s, 512, Wb, 512, A2, cnt, bmsg);
    gemm_gru<<<NN / 32, 256, 0, stream>>>(A2, Wgru, biasg);
  }

  gate_k<<<NN / 16, 256, 0, stream>>>(A2, Wg, bg, gate);
  gemm_k<2><<<dim3(NN / 128, 4), 256, 0, stream>>>(A2 + 256, 384, Wn2gb, 128, ghg, bn2g, gate);
  reduce_k<<<GG, 256, 0, stream>>>(ghg, ptr, hgraph);
  final_k<<<GG / 16, 256, 0, stream>>>(hgraph, Wloc, bloc, Wlv, blv, out);
}

// Round 3
// 1536.564 us; speedup vs baseline: 1.1679x; 1.1679x over previous
//
#include <hip/hip_runtime.h>
#include <cstdint>
#include <cstddef>

#define NN 131072
#define EE 524288
#define GG 4096
#define NPASS 4

typedef __attribute__((ext_vector_type(4))) float f32x4;
typedef __attribute__((ext_vector_type(8))) short bfrag;

__device__ __forceinline__ unsigned short f2bf(float f) {
  union { float f; unsigned u; } v; v.f = f;
  unsigned r = v.u + 0x7fffu + ((v.u >> 16) & 1u);
  return (unsigned short)(r >> 16);
}
__device__ __forceinline__ float bf2f(unsigned short h) {
  union { unsigned u; float f; } v; v.u = ((unsigned)h) << 16;
  return v.f;
}
__device__ __forceinline__ unsigned pack2(float x, float y) {
  return (unsigned)f2bf(x) | ((unsigned)f2bf(y) << 16);
}
__device__ __forceinline__ float sigm(float x) { return 1.f / (1.f + __expf(-x)); }

// async global->LDS 16B: LDS dest is wave-uniform base + lane*16
__device__ __forceinline__ void cp16(unsigned short* l, const unsigned short* g) {
  __builtin_amdgcn_global_load_lds(
      (const __attribute__((address_space(1))) unsigned int*)g,
      (__attribute__((address_space(3))) unsigned int*)l, 16, 0, 0);
}

// ---------------- weight prep ----------------
__global__ void prep_wb(const float* __restrict__ Wmsg, unsigned short* __restrict__ Wb) {
  int idx = blockIdx.x * 256 + threadIdx.x;  // 256*512
  if (idx >= 256 * 512) return;
  int m = idx >> 9, k = idx & 511;
  int t = k >> 7, d = k & 127;
  Wb[idx] = f2bf(Wmsg[((size_t)t * 256 + m) * 128 + d]);
}

__global__ void prep_wgru(const float* __restrict__ Wih, const float* __restrict__ Whh,
                          unsigned short* __restrict__ Wgru) {
  int idx = blockIdx.x * 256 + threadIdx.x;  // 512*384
  if (idx >= 512 * 384) return;
  int j = idx / 384, kk = idx % 384;
  float v;
  if (kk < 256) v = (j < 384) ? Wih[j * 256 + kk] : 0.f;
  else          v = (j < 256) ? Whh[j * 128 + (kk - 256)]
                   : ((j >= 384) ? Whh[(j - 128) * 128 + (kk - 256)] : 0.f);
  Wgru[idx] = f2bf(v);
}

__global__ void prep_bias(const float* __restrict__ bih, const float* __restrict__ bhh,
                          float* __restrict__ biasg) {
  int j = blockIdx.x * 256 + threadIdx.x;
  if (j >= 512) return;
  biasg[j] = (j < 256) ? (bih[j] + bhh[j]) : (j < 384 ? bih[j] : bhh[j - 128]);
}

__global__ void prep_wn2g(const float* __restrict__ Wn, unsigned short* __restrict__ Wo) {
  int idx = blockIdx.x * 256 + threadIdx.x;  // 512*128
  if (idx >= 512 * 128) return;
  Wo[idx] = f2bf(Wn[idx]);
}

// ---------------- init ----------------
__global__ void init_h(const int* __restrict__ nt, const float* __restrict__ emb,
                       unsigned short* __restrict__ A2) {
  size_t idx = (size_t)blockIdx.x * 256 + threadIdx.x;  // N*128
  int n = (int)(idx >> 7), d = (int)(idx & 127);
  A2[(size_t)n * 384 + 256 + d] = f2bf(emb[(size_t)nt[n] * 128 + d]);
}

// ---------------- CSR build (once per call) ----------------
__global__ void deg_k(const int* __restrict__ edst, int* __restrict__ deg) {
  int e = blockIdx.x * 256 + threadIdx.x;
  if (e >= EE) return;
  atomicAdd(&deg[edst[e]], 1);
}

__global__ void cnt_k(const int* __restrict__ edst, const int* __restrict__ etype,
                      float* __restrict__ cnt) {
  int e = blockIdx.x * 256 + threadIdx.x;
  if (e >= EE) return;
  unsafeAtomicAdd(&cnt[(size_t)edst[e] * 4 + etype[e]], 1.0f);
}

__global__ __launch_bounds__(1024) void scan_k(const int* __restrict__ deg,
                                               int* __restrict__ rowptr,
                                               int* __restrict__ cursor) {
  __shared__ int part[1024];
  int t = threadIdx.x;
  int base = t * 128;
  int s = 0;
  for (int i = 0; i < 128; i++) s += deg[base + i];
  part[t] = s;
  __syncthreads();
  for (int off = 1; off < 1024; off <<= 1) {
    int v = (t >= off) ? part[t - off] : 0;
    __syncthreads();
    part[t] += v;
    __syncthreads();
  }
  int run = part[t] - s;  // exclusive prefix
  for (int i = 0; i < 128; i++) {
    rowptr[base + i] = run;
    cursor[base + i] = run;
    run += deg[base + i];
  }
  if (t == 1023) rowptr[NN] = run;
}

__global__ void fill_k(const int* __restrict__ esrc, const int* __restrict__ edst,
                       const int* __restrict__ etype, int* __restrict__ cursor,
                       unsigned* __restrict__ epack) {
  int e = blockIdx.x * 256 + threadIdx.x;
  if (e >= EE) return;
  int pos = atomicAdd(&cursor[edst[e]], 1);
  epack[pos] = ((unsigned)etype[e] << 17) | (unsigned)esrc[e];
}

// ---------------- per-pass aggregation: s[n, t*128+d] = sum h[src] (bf16 out) ----------------
__global__ __launch_bounds__(256) void agg_k(const int* __restrict__ rowptr,
                                             const unsigned* __restrict__ epack,
                                             const unsigned short* __restrict__ A2,
                                             unsigned short* __restrict__ s) {
  int n = blockIdx.x * 4 + (threadIdx.x >> 6);
  int lane = threadIdx.x & 63;
  int beg = rowptr[n], end = rowptr[n + 1];
  const unsigned short* hbase = A2 + 256 + lane * 2;
  float a0 = 0.f, a1 = 0.f, b0 = 0.f, b1 = 0.f;
  float c0 = 0.f, c1 = 0.f, d0 = 0.f, d1 = 0.f;
  for (int base = beg; base < end; base += 64) {
    int cnt = end - base;
    if (cnt > 64) cnt = 64;
    int mye = base + lane;
    unsigned ep = (mye < end) ? epack[mye] : 0u;  // coalesced pre-load
    for (int j = 0; j < cnt; j++) {
      unsigned p = (unsigned)__shfl((int)ep, j);  // wave-uniform edge
      int src = (int)(p & 0x1FFFFu);
      int t = (int)(p >> 17);
      unsigned hv = *(const unsigned*)&hbase[(size_t)src * 384];
      float v0 = bf2f((unsigned short)(hv & 0xffffu));
      float v1 = bf2f((unsigned short)(hv >> 16));
      if (t == 0)      { a0 += v0; a1 += v1; }
      else if (t == 1) { b0 += v0; b1 += v1; }
      else if (t == 2) { c0 += v0; c1 += v1; }
      else             { d0 += v0; d1 += v1; }
    }
  }
  unsigned short* srow = s + (size_t)n * 512;
  *(unsigned*)&srow[0 * 128 + lane * 2] = pack2(a0, a1);
  *(unsigned*)&srow[1 * 128 + lane * 2] = pack2(b0, b1);
  *(unsigned*)&srow[2 * 128 + lane * 2] = pack2(c0, c1);
  *(unsigned*)&srow[3 * 128 + lane * 2] = pack2(d0, d1);
}

// ---------------- 128x128-tile MFMA GEMM: out = A(NxK,bf16) @ W(JxK)^T ----------------
// MODE 0: +cnt*b_msg, relu -> bf16 into A2 m-part (ld 384)
// MODE 1: +bias           -> bf16 U (ld 512)
// MODE 2: (+b_n2g)*gate[i] -> bf16 ghg (ld 512)
template <int MODE>
__global__ __launch_bounds__(256) void gemm_k(const unsigned short* __restrict__ A, int lda,
                                              const unsigned short* __restrict__ W, int K,
                                              void* __restrict__ Out,
                                              const float* __restrict__ aux1,
                                              const float* __restrict__ aux2) {
  __shared__ __align__(16) unsigned short As[128 * 32];
  __shared__ __align__(16) unsigned short Ws[128 * 32];
  int i0 = blockIdx.x * 128;
  int j0 = blockIdx.y * 128;
  int tid = threadIdx.x;
  int lane = tid & 63, w = tid >> 6;
  int wi = w >> 1, wj = w & 1;
  int q = lane >> 4, r = lane & 15;

  f32x4 acc[4][4];
#pragma unroll
  for (int a = 0; a < 4; a++)
#pragma unroll
    for (int b = 0; b < 4; b++) acc[a][b] = f32x4{0.f, 0.f, 0.f, 0.f};

  int row = tid >> 2;        // 0..63
  int scol = (tid & 3) * 8;  // 0,8,16,24
  const unsigned short* Ag0 = A + (size_t)(i0 + row) * lda + scol;
  const unsigned short* Ag1 = A + (size_t)(i0 + row + 64) * lda + scol;
  const unsigned short* Wg0 = W + (size_t)(j0 + row) * K + scol;
  const unsigned short* Wg1 = W + (size_t)(j0 + row + 64) * K + scol;
  unsigned short* AsW = &As[w * 512];  // wave-uniform LDS base (byte = w*1024)
  unsigned short* WsW = &Ws[w * 512];

  for (int k0 = 0; k0 < K; k0 += 32) {
    cp16(AsW, Ag0 + k0);
    cp16(AsW + 2048, Ag1 + k0);
    cp16(WsW, Wg0 + k0);
    cp16(WsW + 2048, Wg1 + k0);
    __syncthreads();
    bfrag af[4], bfr[4];
#pragma unroll
    for (int rt = 0; rt < 4; rt++)
      af[rt] = *(const bfrag*)&As[(wi * 64 + rt * 16 + r) * 32 + q * 8];
#pragma unroll
    for (int ct = 0; ct < 4; ct++)
      bfr[ct] = *(const bfrag*)&Ws[(wj * 64 + ct * 16 + r) * 32 + q * 8];
#pragma unroll
    for (int rt = 0; rt < 4; rt++)
#pragma unroll
      for (int ct = 0; ct < 4; ct++)
        acc[rt][ct] =
            __builtin_amdgcn_mfma_f32_16x16x32_bf16(af[rt], bfr[ct], acc[rt][ct], 0, 0, 0);
    __syncthreads();
  }

#pragma unroll
  for (int rt = 0; rt < 4; rt++) {
#pragma unroll
    for (int ct = 0; ct < 4; ct++) {
#pragma unroll
      for (int reg = 0; reg < 4; reg++) {
        int i = i0 + wi * 64 + rt * 16 + q * 4 + reg;
        int j = j0 + wj * 64 + ct * 16 + r;
        float v = acc[rt][ct][reg];
        if (MODE == 0) {
          const float* cnt = aux1 + (size_t)i * 4;
          v += cnt[0] * aux2[j] + cnt[1] * aux2[256 + j] + cnt[2] * aux2[512 + j] +
               cnt[3] * aux2[768 + j];
          v = v > 0.f ? v : 0.f;
          ((unsigned short*)Out)[(size_t)i * 384 + j] = f2bf(v);
        } else if (MODE == 1) {
          v += aux1[j];
          ((unsigned short*)Out)[(size_t)i * 512 + j] = f2bf(v);
        } else {
          v = (v + aux1[j]) * aux2[i];
          ((unsigned short*)Out)[(size_t)i * 512 + j] = f2bf(v);
        }
      }
    }
  }
}

// ---------------- GRU elementwise (U bf16, ld 512) ----------------
__global__ __launch_bounds__(256) void gru_ew(const unsigned short* __restrict__ U,
                                              unsigned short* __restrict__ A2) {
  size_t idx = (size_t)blockIdx.x * 256 + threadIdx.x;  // N*64
  int n = (int)(idx >> 6), dp = (int)(idx & 63) * 2;
  const unsigned short* u = U + (size_t)n * 512 + dp;
  unsigned ur = *(const unsigned*)(u);
  unsigned uz = *(const unsigned*)(u + 128);
  unsigned un = *(const unsigned*)(u + 256);
  unsigned uh = *(const unsigned*)(u + 384);
  unsigned short* hp = A2 + (size_t)n * 384 + 256 + dp;
  unsigned hv = *(unsigned*)hp;
  float out0, out1;
  {
    float rg = sigm(bf2f((unsigned short)(ur & 0xffffu)));
    float zg = sigm(bf2f((unsigned short)(uz & 0xffffu)));
    float ng = tanhf(bf2f((unsigned short)(un & 0xffffu)) +
                     rg * bf2f((unsigned short)(uh & 0xffffu)));
    float hold = bf2f((unsigned short)(hv & 0xffffu));
    out0 = (1.f - zg) * ng + zg * hold;
  }
  {
    float rg = sigm(bf2f((unsigned short)(ur >> 16)));
    float zg = sigm(bf2f((unsigned short)(uz >> 16)));
    float ng = tanhf(bf2f((unsigned short)(un >> 16)) + rg * bf2f((unsigned short)(uh >> 16)));
    float hold = bf2f((unsigned short)(hv >> 16));
    out1 = (1.f - zg) * ng + zg * hold;
  }
  *(unsigned*)hp = pack2(out0, out1);
}

// ---------------- readout ----------------
__global__ __launch_bounds__(256) void gate_k(const unsigned short* __restrict__ A2,
                                              const float* __restrict__ Wg,
                                              const float* __restrict__ bg,
                                              float* __restrict__ gate) {
  __shared__ float wg[128];
  if (threadIdx.x < 128) wg[threadIdx.x] = Wg[threadIdx.x];
  __syncthreads();
  int g = threadIdx.x >> 4, sub = threadIdx.x & 15;
  int n = blockIdx.x * 16 + g;
  const unsigned short* hr = A2 + (size_t)n * 384 + 256;
  float p = 0.f;
  for (int k = sub; k < 128; k += 16) p += bf2f(hr[k]) * wg[k];
  p += __shfl_xor(p, 1);
  p += __shfl_xor(p, 2);
  p += __shfl_xor(p, 4);
  p += __shfl_xor(p, 8);
  if (sub == 0) gate[n] = sigm(p + bg[0]);
}

__global__ __launch_bounds__(256) void reduce_k(const unsigned short* __restrict__ ghg,
                                                const int* __restrict__ ptr,
                                                float* __restrict__ hgraph) {
  int g = blockIdx.x;
  int start = ptr[g], end = ptr[g + 1];
  int c = threadIdx.x;
  float a0 = 0.f, a1 = 0.f;
  for (int n = start; n < end; n++) {
    const unsigned short* row = ghg + (size_t)n * 512;
    a0 += bf2f(row[c]);
    a1 += bf2f(row[c + 256]);
  }
  hgraph[(size_t)g * 512 + c] = a0;
  hgraph[(size_t)g * 512 + c + 256] = a1;
}

__global__ __launch_bounds__(256) void final_k(const float* __restrict__ hgraph,
                                               const float* __restrict__ Wloc,
                                               const float* __restrict__ bloc,
                                               const float* __restrict__ Wlv,
                                               const float* __restrict__ blv,
                                               float* __restrict__ out) {
  __shared__ float hs[16 * 512];
  int bid = blockIdx.x;
  const float* base = hgraph + (size_t)bid * 16 * 512;
  for (int x = threadIdx.x; x < 16 * 512 / 4; x += 256)
    ((float4*)hs)[x] = ((const float4*)base)[x];
  __syncthreads();
  int j = threadIdx.x;
  const float* wrow = (j < 128) ? (Wloc + (size_t)j * 512) : (Wlv + (size_t)(j - 128) * 512);
  float bias = (j < 128) ? bloc[j] : blv[j - 128];
  float acc[16];
#pragma unroll
  for (int rr = 0; rr < 16; rr++) acc[rr] = bias;
  for (int k = 0; k < 512; k++) {
    float wv = wrow[k];
#pragma unroll
    for (int rr = 0; rr < 16; rr++) acc[rr] += hs[rr * 512 + k] * wv;
  }
#pragma unroll
  for (int rr = 0; rr < 16; rr++) {
    int g = bid * 16 + rr;
    size_t o = (j < 128) ? ((size_t)g * 128 + j)
                         : ((size_t)GG * 128 + (size_t)g * 128 + (j - 128));
    out[o] = acc[rr];
  }
}

extern "C" void kernel_launch(void* const* d_in, const int* in_sizes, int n_in,
                              void* d_out, int out_size, void* d_ws, size_t ws_size,
                              hipStream_t stream) {
  const int* node_types = (const int*)d_in[0];
  const int* esrc = (const int*)d_in[1];
  const int* edst = (const int*)d_in[2];
  const int* etype = (const int*)d_in[3];
  const int* ptr = (const int*)d_in[4];
  const float* emb = (const float*)d_in[5];
  const float* Wmsg = (const float*)d_in[6];
  const float* bmsg = (const float*)d_in[7];
  const float* Wih = (const float*)d_in[8];
  const float* Whh = (const float*)d_in[9];
  const float* bih = (const float*)d_in[10];
  const float* bhh = (const float*)d_in[11];
  const float* Wg = (const float*)d_in[12];
  const float* bg = (const float*)d_in[13];
  const float* Wn2g = (const float*)d_in[14];
  const float* bn2g = (const float*)d_in[15];
  const float* Wloc = (const float*)d_in[16];
  const float* bloc = (const float*)d_in[17];
  const float* Wlv = (const float*)d_in[18];
  const float* blv = (const float*)d_in[19];
  float* out = (float*)d_out;

  char* ws = (char*)d_ws;
  size_t off = 0;
  unsigned short* s = (unsigned short*)(ws);  // N x 512 bf16 (128 MB); U and ghg alias
  unsigned short* U = s;
  unsigned short* ghg = s;
  off += (size_t)NN * 512 * 2;
  unsigned short* A2 = (unsigned short*)(ws + off);  // N x 384 bf16: [m(256) | h(128)]
  off += (size_t)NN * 384 * 2;
  float* cnt = (float*)(ws + off);
  off += (size_t)NN * 4 * 4;
  int* deg = (int*)(ws + off);
  off += (size_t)NN * 4;
  int* rowptr = (int*)(ws + off);
  off += (size_t)(NN + 64) * 4;
  int* cursor = (int*)(ws + off);
  off += (size_t)NN * 4;
  unsigned* epack = (unsigned*)(ws + off);
  off += (size_t)EE * 4;
  float* hgraph = (float*)(ws + off);
  off += (size_t)GG * 512 * 4;
  float* gate = (float*)(ws + off);
  off += (size_t)NN * 4;
  unsigned short* Wb = (unsigned short*)(ws + off);
  off += 256 * 512 * 2;
  unsigned short* Wgru = (unsigned short*)(ws + off);
  off += 512 * 384 * 2;
  float* biasg = (float*)(ws + off);
  off += 512 * 4;
  unsigned short* Wn2gb = (unsigned short*)(ws + off);
  off += 512 * 128 * 2;

  hipMemsetAsync(deg, 0, (size_t)NN * 4, stream);
  hipMemsetAsync(cnt, 0, (size_t)NN * 16, stream);
  prep_wb<<<512, 256, 0, stream>>>(Wmsg, Wb);
  prep_wgru<<<768, 256, 0, stream>>>(Wih, Whh, Wgru);
  prep_bias<<<2, 256, 0, stream>>>(bih, bhh, biasg);
  prep_wn2g<<<256, 256, 0, stream>>>(Wn2g, Wn2gb);
  init_h<<<NN * 128 / 256, 256, 0, stream>>>(node_types, emb, A2);
  deg_k<<<EE / 256, 256, 0, stream>>>(edst, deg);
  cnt_k<<<EE / 256, 256, 0, stream>>>(edst, etype, cnt);
  scan_k<<<1, 1024, 0, stream>>>(deg, rowptr, cursor);
  fill_k<<<EE / 256, 256, 0, stream>>>(esrc, edst, etype, cursor, epack);

  for (int p = 0; p < NPASS; p++) {
    agg_k<<<NN / 4, 256, 0, stream>>>(rowptr, epack, A2, s);
    gemm_k<0><<<dim3(NN / 128, 2), 256, 0, stream>>>(s, 512, Wb, 512, A2, cnt, bmsg);
    gemm_k<1><<<dim3(NN / 128, 4), 256, 0, stream>>>(A2, 384, Wgru, 384, U, biasg, nullptr);
    gru_ew<<<NN * 64 / 256, 256, 0, stream>>>(U, A2);
  }

  gate_k<<<NN / 16, 256, 0, stream>>>(A2, Wg, bg, gate);
  gemm_k<2><<<dim3(NN / 128, 4), 256, 0, stream>>>(A2 + 256, 384, Wn2gb, 128, ghg, bn2g, gate);
  reduce_k<<<GG, 256, 0, stream>>>(ghg, ptr, hgraph);
  final_k<<<GG / 16, 256, 0, stream>>>(hgraph, Wloc, bloc, Wlv, blv, out);
}

// Round 5
// 1479.338 us; speedup vs baseline: 1.2130x; 1.0387x over previous
//
#include <hip/hip_runtime.h>
#include <cstdint>
#include <cstddef>

#define NN 131072
#define EE 524288
#define GG 4096
#define NPASS 4

typedef __attribute__((ext_vector_type(4))) float f32x4;
typedef __attribute__((ext_vector_type(8))) short bfrag;

__device__ __forceinline__ unsigned short f2bf(float f) {
  union { float f; unsigned u; } v; v.f = f;
  unsigned r = v.u + 0x7fffu + ((v.u >> 16) & 1u);
  return (unsigned short)(r >> 16);
}
__device__ __forceinline__ float bf2f(unsigned short h) {
  union { unsigned u; float f; } v; v.u = ((unsigned)h) << 16;
  return v.f;
}
__device__ __forceinline__ unsigned pack2(float x, float y) {
  return (unsigned)f2bf(x) | ((unsigned)f2bf(y) << 16);
}
__device__ __forceinline__ float sigm(float x) { return 1.f / (1.f + __expf(-x)); }

// async global->LDS 16B: LDS dest is wave-uniform base + lane*16
__device__ __forceinline__ void cp16(unsigned short* l, const unsigned short* g) {
  __builtin_amdgcn_global_load_lds(
      (const __attribute__((address_space(1))) unsigned int*)g,
      (__attribute__((address_space(3))) unsigned int*)l, 16, 0, 0);
}

// ---------------- weight prep ----------------
__global__ void prep_wb(const float* __restrict__ Wmsg, unsigned short* __restrict__ Wb) {
  int idx = blockIdx.x * 256 + threadIdx.x;  // 256*512
  if (idx >= 256 * 512) return;
  int m = idx >> 9, k = idx & 511;
  int t = k >> 7, d = k & 127;
  Wb[idx] = f2bf(Wmsg[((size_t)t * 256 + m) * 128 + d]);
}

// Wgru rows interleaved by gate: out-col = 4*d + g, g in {r,z,n,hn}
__global__ void prep_wgru(const float* __restrict__ Wih, const float* __restrict__ Whh,
                          unsigned short* __restrict__ Wgru) {
  int idx = blockIdx.x * 256 + threadIdx.x;  // 512*384
  if (idx >= 512 * 384) return;
  int j = idx / 384, kk = idx % 384;
  float v;
  if (kk < 256) v = (j < 384) ? Wih[j * 256 + kk] : 0.f;
  else          v = (j < 256) ? Whh[j * 128 + (kk - 256)]
                   : ((j >= 384) ? Whh[(j - 128) * 128 + (kk - 256)] : 0.f);
  int g = (j < 128) ? 0 : (j < 256) ? 1 : (j < 384) ? 2 : 3;
  int d = j & 127;
  Wgru[(size_t)(4 * d + g) * 384 + kk] = f2bf(v);
}

__global__ void prep_bias(const float* __restrict__ bih, const float* __restrict__ bhh,
                          float* __restrict__ biasg) {
  int j = blockIdx.x * 256 + threadIdx.x;
  if (j >= 512) return;
  float v;
  if (j < 256) v = bih[j] + bhh[j];
  else if (j < 384) v = bih[j];
  else v = bhh[j - 128];
  int g = (j < 128) ? 0 : (j < 256) ? 1 : (j < 384) ? 2 : 3;
  int d = j & 127;
  biasg[4 * d + g] = v;
}

__global__ void prep_wn2g(const float* __restrict__ Wn, unsigned short* __restrict__ Wo) {
  int idx = blockIdx.x * 256 + threadIdx.x;  // 512*128
  if (idx >= 512 * 128) return;
  Wo[idx] = f2bf(Wn[idx]);
}

// ---------------- init ----------------
__global__ void init_h(const int* __restrict__ nt, const float* __restrict__ emb,
                       unsigned short* __restrict__ H) {
  size_t idx = (size_t)blockIdx.x * 256 + threadIdx.x;  // N*128
  int n = (int)(idx >> 7), d = (int)(idx & 127);
  H[idx] = f2bf(emb[(size_t)nt[n] * 128 + d]);
}

// ---------------- CSR build (once per call) ----------------
__global__ void deg_k(const int* __restrict__ edst, int* __restrict__ deg) {
  int e = blockIdx.x * 256 + threadIdx.x;
  if (e >= EE) return;
  atomicAdd(&deg[edst[e]], 1);
}

__global__ void cnt_k(const int* __restrict__ edst, const int* __restrict__ etype,
                      float* __restrict__ cnt) {
  int e = blockIdx.x * 256 + threadIdx.x;
  if (e >= EE) return;
  unsafeAtomicAdd(&cnt[(size_t)edst[e] * 4 + etype[e]], 1.0f);
}

__global__ __launch_bounds__(1024) void scan_k(const int* __restrict__ deg,
                                               int* __restrict__ rowptr,
                                               int* __restrict__ cursor) {
  __shared__ int part[1024];
  int t = threadIdx.x;
  int base = t * 128;
  int s = 0;
  for (int i = 0; i < 128; i++) s += deg[base + i];
  part[t] = s;
  __syncthreads();
  for (int off = 1; off < 1024; off <<= 1) {
    int v = (t >= off) ? part[t - off] : 0;
    __syncthreads();
    part[t] += v;
    __syncthreads();
  }
  int run = part[t] - s;  // exclusive prefix
  for (int i = 0; i < 128; i++) {
    rowptr[base + i] = run;
    cursor[base + i] = run;
    run += deg[base + i];
  }
  if (t == 1023) rowptr[NN] = run;
}

__global__ void fill_k(const int* __restrict__ esrc, const int* __restrict__ edst,
                       const int* __restrict__ etype, int* __restrict__ cursor,
                       unsigned* __restrict__ epack) {
  int e = blockIdx.x * 256 + threadIdx.x;
  if (e >= EE) return;
  int pos = atomicAdd(&cursor[edst[e]], 1);
  epack[pos] = ((unsigned)etype[e] << 17) | (unsigned)esrc[e];
}

// ---------------- per-pass aggregation: s[n, t*128+d] = sum h[src] (bf16 out) ----------------
__global__ __launch_bounds__(256) void agg_k(const int* __restrict__ rowptr,
                                             const unsigned* __restrict__ epack,
                                             const unsigned short* __restrict__ H,
                                             unsigned short* __restrict__ s) {
  int n = blockIdx.x * 4 + (threadIdx.x >> 6);
  int lane = threadIdx.x & 63;
  int beg = rowptr[n], end = rowptr[n + 1];
  const unsigned short* hbase = H + lane * 2;
  float a0 = 0.f, a1 = 0.f, b0 = 0.f, b1 = 0.f;
  float c0 = 0.f, c1 = 0.f, d0 = 0.f, d1 = 0.f;
  for (int base = beg; base < end; base += 64) {
    int cnt = end - base;
    if (cnt > 64) cnt = 64;
    int mye = base + lane;
    unsigned ep = (mye < end) ? epack[mye] : 0u;  // coalesced pre-load
    for (int j = 0; j < cnt; j++) {
      unsigned p = (unsigned)__shfl((int)ep, j);  // wave-uniform edge
      int src = (int)(p & 0x1FFFFu);
      int t = (int)(p >> 17);
      unsigned hv = *(const unsigned*)&hbase[(size_t)src * 128];
      float v0 = bf2f((unsigned short)(hv & 0xffffu));
      float v1 = bf2f((unsigned short)(hv >> 16));
      if (t == 0)      { a0 += v0; a1 += v1; }
      else if (t == 1) { b0 += v0; b1 += v1; }
      else if (t == 2) { c0 += v0; c1 += v1; }
      else             { d0 += v0; d1 += v1; }
    }
  }
  unsigned short* srow = s + (size_t)n * 512;
  *(unsigned*)&srow[0 * 128 + lane * 2] = pack2(a0, a1);
  *(unsigned*)&srow[1 * 128 + lane * 2] = pack2(b0, b1);
  *(unsigned*)&srow[2 * 128 + lane * 2] = pack2(c0, c1);
  *(unsigned*)&srow[3 * 128 + lane * 2] = pack2(d0, d1);
}

// ---------------- 128x256-tile MFMA GEMM: out = A(NxK,bf16) @ W(JxK)^T ----------------
// A is split: cols [0,ksplit) from A0 (lda0), cols [ksplit,K) from A1 (lda1).
// MODE 0: +cnt*b_msg, relu -> bf16 into Out cols [0,256) with ld 512 (in-place into s)
// MODE 1: fused GRU (W cols interleaved 4*d+g): reads Hold, writes Hnew; no Out
// MODE 2: (+b_n2g)*gate[i] -> bf16 ghg (ld 512)
template <int MODE>
__global__ __launch_bounds__(256, 2) void gemm_k(
    const unsigned short* __restrict__ A0, int lda0, int ksplit,
    const unsigned short* __restrict__ A1, int lda1,
    const unsigned short* __restrict__ W, int K,
    unsigned short* __restrict__ Out,
    const float* __restrict__ aux1, const float* __restrict__ aux2,
    const unsigned short* __restrict__ Hold, unsigned short* __restrict__ Hnew) {
  __shared__ __align__(16) unsigned short As[128 * 32];
  __shared__ __align__(16) unsigned short Ws[256 * 32];
  int i0 = blockIdx.x * 128;
  int j0 = blockIdx.y * 256;
  int tid = threadIdx.x;
  int lane = tid & 63, w = tid >> 6;
  int wi = w >> 1, wj = w & 1;
  int q = lane >> 4, r = lane & 15;

  f32x4 acc[4][8];
#pragma unroll
  for (int a = 0; a < 4; a++)
#pragma unroll
    for (int b = 0; b < 8; b++) acc[a][b] = f32x4{0.f, 0.f, 0.f, 0.f};

  int row = tid >> 2;        // 0..63
  int scol = (tid & 3) * 8;  // 0,8,16,24
  unsigned short* AsW = &As[w * 512];  // wave-uniform LDS base
  unsigned short* WsW = &Ws[w * 512];

  for (int k0 = 0; k0 < K; k0 += 32) {
#pragma unroll
    for (int c = 0; c < 2; c++) {
      int gr = i0 + row + c * 64;
      const unsigned short* asrc =
          (k0 < ksplit) ? A0 + (size_t)gr * lda0 + k0 + scol
                        : A1 + (size_t)gr * lda1 + (k0 - ksplit) + scol;
      cp16(AsW + c * 2048, asrc);
    }
#pragma unroll
    for (int c = 0; c < 4; c++)
      cp16(WsW + c * 2048, W + (size_t)(j0 + row + c * 64) * K + k0 + scol);
    __syncthreads();
    bfrag af[4];
#pragma unroll
    for (int rt = 0; rt < 4; rt++)
      af[rt] = *(const bfrag*)&As[(wi * 64 + rt * 16 + r) * 32 + q * 8];
#pragma unroll
    for (int ct = 0; ct < 8; ct++) {
      bfrag bfr = *(const bfrag*)&Ws[(wj * 128 + ct * 16 + r) * 32 + q * 8];
#pragma unroll
      for (int rt = 0; rt < 4; rt++)
        acc[rt][ct] =
            __builtin_amdgcn_mfma_f32_16x16x32_bf16(af[rt], bfr, acc[rt][ct], 0, 0, 0);
    }
    __syncthreads();
  }

  if (MODE == 1) {
    // fused GRU epilogue: columns are 4*d+g; 4-lane quad holds the 4 gates
    int rr = r & 3;
    bool b0 = (lane & 1) != 0, b1 = (lane & 2) != 0;
#pragma unroll
    for (int ct = 0; ct < 8; ct++) {
      float bias = aux1[j0 + wj * 128 + ct * 16 + r];
      int d = (j0 >> 2) + wj * 32 + ct * 4 + (r >> 2);
#pragma unroll
      for (int rt = 0; rt < 4; rt++) {
        float v0 = acc[rt][ct][0] + bias;
        float v1 = acc[rt][ct][1] + bias;
        float v2 = acc[rt][ct][2] + bias;
        float v3 = acc[rt][ct][3] + bias;
        float t, rcv;
        // quad 4x4 transpose: after this, vk = gate k for row q*4+rr at dim d
        t = b0 ? v0 : v1; rcv = __shfl_xor(t, 1);
        v0 = b0 ? rcv : v0; v1 = b0 ? v1 : rcv;
        t = b0 ? v2 : v3; rcv = __shfl_xor(t, 1);
        v2 = b0 ? rcv : v2; v3 = b0 ? v3 : rcv;
        t = b1 ? v0 : v2; rcv = __shfl_xor(t, 2);
        v0 = b1 ? rcv : v0; v2 = b1 ? v2 : rcv;
        t = b1 ? v1 : v3; rcv = __shfl_xor(t, 2);
        v1 = b1 ? rcv : v1; v3 = b1 ? v3 : rcv;
        int i = i0 + wi * 64 + rt * 16 + q * 4 + rr;
        size_t hoff = (size_t)i * 128 + d;
        float hold = bf2f(Hold[hoff]);
        float rg = sigm(v0), zg = sigm(v1);
        float ng = tanhf(v2 + rg * v3);
        Hnew[hoff] = f2bf((1.f - zg) * ng + zg * hold);
      }
    }
  } else {
#pragma unroll
    for (int ct = 0; ct < 8; ct++) {
      int j = j0 + wj * 128 + ct * 16 + r;
#pragma unroll
      for (int rt = 0; rt < 4; rt++) {
#pragma unroll
        for (int reg = 0; reg < 4; reg++) {
          int i = i0 + wi * 64 + rt * 16 + q * 4 + reg;
          float v = acc[rt][ct][reg];
          if (MODE == 0) {
            float4 c4 = *(const float4*)&aux1[(size_t)i * 4];
            v += c4.x * aux2[j] + c4.y * aux2[256 + j] + c4.z * aux2[512 + j] +
                 c4.w * aux2[768 + j];
            v = v > 0.f ? v : 0.f;
            Out[(size_t)i * 512 + j] = f2bf(v);  // in-place: first 256 cols of s
          } else {
            v = (v + aux1[j]) * aux2[i];
            Out[(size_t)i * 512 + j] = f2bf(v);
          }
        }
      }
    }
  }
}

// ---------------- readout ----------------
__global__ __launch_bounds__(256) void gate_k(const unsigned short* __restrict__ H,
                                              const float* __restrict__ Wg,
                                              const float* __restrict__ bg,
                                              float* __restrict__ gate) {
  __shared__ float wg[128];
  if (threadIdx.x < 128) wg[threadIdx.x] = Wg[threadIdx.x];
  __syncthreads();
  int g = threadIdx.x >> 4, sub = threadIdx.x & 15;
  int n = blockIdx.x * 16 + g;
  const unsigned short* hr = H + (size_t)n * 128;
  float p = 0.f;
  for (int k = sub; k < 128; k += 16) p += bf2f(hr[k]) * wg[k];
  p += __shfl_xor(p, 1);
  p += __shfl_xor(p, 2);
  p += __shfl_xor(p, 4);
  p += __shfl_xor(p, 8);
  if (sub == 0) gate[n] = sigm(p + bg[0]);
}

__global__ __launch_bounds__(256) void reduce_k(const unsigned short* __restrict__ ghg,
                                                const int* __restrict__ ptr,
                                                float* __restrict__ hgraph) {
  int g = blockIdx.x;
  int start = ptr[g], end = ptr[g + 1];
  int c = threadIdx.x;
  float a0 = 0.f, a1 = 0.f;
  for (int n = start; n < end; n++) {
    const unsigned short* row = ghg + (size_t)n * 512;
    a0 += bf2f(row[c]);
    a1 += bf2f(row[c + 256]);
  }
  hgraph[(size_t)g * 512 + c] = a0;
  hgraph[(size_t)g * 512 + c + 256] = a1;
}

__global__ __launch_bounds__(256) void final_k(const float* __restrict__ hgraph,
                                               const float* __restrict__ Wloc,
                                               const float* __restrict__ bloc,
                                               const float* __restrict__ Wlv,
                                               const float* __restrict__ blv,
                                               float* __restrict__ out) {
  __shared__ float hs[16 * 512];
  int bid = blockIdx.x;
  const float* base = hgraph + (size_t)bid * 16 * 512;
  for (int x = threadIdx.x; x < 16 * 512 / 4; x += 256)
    ((float4*)hs)[x] = ((const float4*)base)[x];
  __syncthreads();
  int j = threadIdx.x;
  const float* wrow = (j < 128) ? (Wloc + (size_t)j * 512) : (Wlv + (size_t)(j - 128) * 512);
  float bias = (j < 128) ? bloc[j] : blv[j - 128];
  float acc[16];
#pragma unroll
  for (int rr = 0; rr < 16; rr++) acc[rr] = bias;
  for (int k = 0; k < 512; k++) {
    float wv = wrow[k];
#pragma unroll
    for (int rr = 0; rr < 16; rr++) acc[rr] += hs[rr * 512 + k] * wv;
  }
#pragma unroll
  for (int rr = 0; rr < 16; rr++) {
    int g = bid * 16 + rr;
    size_t o = (j < 128) ? ((size_t)g * 128 + j)
                         : ((size_t)GG * 128 + (size_t)g * 128 + (j - 128));
    out[o] = acc[rr];
  }
}

extern "C" void kernel_launch(void* const* d_in, const int* in_sizes, int n_in,
                              void* d_out, int out_size, void* d_ws, size_t ws_size,
                              hipStream_t stream) {
  const int* node_types = (const int*)d_in[0];
  const int* esrc = (const int*)d_in[1];
  const int* edst = (const int*)d_in[2];
  const int* etype = (const int*)d_in[3];
  const int* ptr = (const int*)d_in[4];
  const float* emb = (const float*)d_in[5];
  const float* Wmsg = (const float*)d_in[6];
  const float* bmsg = (const float*)d_in[7];
  const float* Wih = (const float*)d_in[8];
  const float* Whh = (const float*)d_in[9];
  const float* bih = (const float*)d_in[10];
  const float* bhh = (const float*)d_in[11];
  const float* Wg = (const float*)d_in[12];
  const float* bg = (const float*)d_in[13];
  const float* Wn2g = (const float*)d_in[14];
  const float* bn2g = (const float*)d_in[15];
  const float* Wloc = (const float*)d_in[16];
  const float* bloc = (const float*)d_in[17];
  const float* Wlv = (const float*)d_in[18];
  const float* blv = (const float*)d_in[19];
  float* out = (float*)d_out;

  char* ws = (char*)d_ws;
  size_t off = 0;
  unsigned short* s = (unsigned short*)(ws);  // N x 512 bf16; Mbuf (cols 0-255) and ghg alias
  unsigned short* ghg = s;
  off += (size_t)NN * 512 * 2;
  unsigned short* H0 = (unsigned short*)(ws + off);  // N x 128 bf16
  off += (size_t)NN * 128 * 2;
  unsigned short* H1 = (unsigned short*)(ws + off);
  off += (size_t)NN * 128 * 2;
  float* cnt = (float*)(ws + off);
  off += (size_t)NN * 4 * 4;
  int* deg = (int*)(ws + off);
  off += (size_t)NN * 4;
  int* rowptr = (int*)(ws + off);
  off += (size_t)(NN + 64) * 4;
  int* cursor = (int*)(ws + off);
  off += (size_t)NN * 4;
  unsigned* epack = (unsigned*)(ws + off);
  off += (size_t)EE * 4;
  float* hgraph = (float*)(ws + off);
  off += (size_t)GG * 512 * 4;
  float* gate = (float*)(ws + off);
  off += (size_t)NN * 4;
  unsigned short* Wb = (unsigned short*)(ws + off);
  off += 256 * 512 * 2;
  unsigned short* Wgru = (unsigned short*)(ws + off);
  off += 512 * 384 * 2;
  float* biasg = (float*)(ws + off);
  off += 512 * 4;
  unsigned short* Wn2gb = (unsigned short*)(ws + off);
  off += 512 * 128 * 2;
  // total ~217 MB < 256 MiB ws

  hipMemsetAsync(deg, 0, (size_t)NN * 4, stream);
  hipMemsetAsync(cnt, 0, (size_t)NN * 16, stream);
  prep_wb<<<512, 256, 0, stream>>>(Wmsg, Wb);
  prep_wgru<<<768, 256, 0, stream>>>(Wih, Whh, Wgru);
  prep_bias<<<2, 256, 0, stream>>>(bih, bhh, biasg);
  prep_wn2g<<<256, 256, 0, stream>>>(Wn2g, Wn2gb);
  init_h<<<NN * 128 / 256, 256, 0, stream>>>(node_types, emb, H0);
  deg_k<<<EE / 256, 256, 0, stream>>>(edst, deg);
  cnt_k<<<EE / 256, 256, 0, stream>>>(edst, etype, cnt);
  scan_k<<<1, 1024, 0, stream>>>(deg, rowptr, cursor);
  fill_k<<<EE / 256, 256, 0, stream>>>(esrc, edst, etype, cursor, epack);

  unsigned short* Hc = H0;
  unsigned short* Hn = H1;
  for (int p = 0; p < NPASS; p++) {
    agg_k<<<NN / 4, 256, 0, stream>>>(rowptr, epack, Hc, s);
    // m = relu(s @ Wb^T + cnt*b_msg) written in-place into s cols [0,256)
    gemm_k<0><<<dim3(NN / 128, 1), 256, 0, stream>>>(s, 512, 512, s, 512, Wb, 512, s,
                                                     cnt, bmsg, nullptr, nullptr);
    // fused GRU: A = [m (s cols 0-255) | Hc], W interleaved; writes Hn
    gemm_k<1><<<dim3(NN / 128, 2), 256, 0, stream>>>(s, 512, 256, Hc, 128, Wgru, 384,
                                                     nullptr, biasg, nullptr, Hc, Hn);
    unsigned short* tmp = Hc; Hc = Hn; Hn = tmp;
  }

  gate_k<<<NN / 16, 256, 0, stream>>>(Hc, Wg, bg, gate);
  gemm_k<2><<<dim3(NN / 128, 2), 256, 0, stream>>>(Hc, 128, 128, Hc, 128, Wn2gb, 128, ghg,
                                                   bn2g, gate, nullptr, nullptr);
  reduce_k<<<GG, 256, 0, stream>>>(ghg, ptr, hgraph);
  final_k<<<GG / 16, 256, 0, stream>>>(hgraph, Wloc, bloc, Wlv, blv, out);
}